// Round 1
// baseline (1851.249 us; speedup 1.0000x reference)
//
#include <hip/hip_runtime.h>
#include <stdint.h>

// ---------------------------------------------------------------------------
// DecoderRNN: 100-step LSTM + additive attention + 3-layer MLP, B=1.
// Strategy: persistent 39-WG kernel, all weights LDS-resident, 2 device-scope
// barriers per step, MLP pipelined off the critical path.
// ---------------------------------------------------------------------------

static constexpr int   NWG = 39;                 // 32 main + 4 MLP1 + 2 MLP2 + 1 MLP3
static constexpr float L2E = 1.44269504088896341f;   // log2(e)
static constexpr float K2  = 2.88539008177792681f;   // 2*log2(e)

// workspace layout (float offsets)
static constexpr size_t OFF_BC   = 0;            // [2048][256] (VOut+att_b)*K2
static constexpr size_t OFF_YG   = 524288;       // [100][1024] y@W_ih.T + b_ih + b_hh
static constexpr size_t OFF_GRAW = 626688;       // [100][1024] full gate preacts
static constexpr size_t OFF_WSG  = 729088;       // [100][256]  WS*K2
static constexpr size_t OFF_PM   = 754688;       // [100][32]   per-WG score max
static constexpr size_t OFF_PS   = 757888;       // [100][32]   per-WG exp-sum
static constexpr size_t OFF_PV   = 761088;       // [100][32][256] per-WG partial ctx
static constexpr size_t OFF_CTXH = 1580288;      // [100][256] ctx history
static constexpr size_t OFF_CLH  = 1605888;      // [100][256] cLSTM history
static constexpr size_t OFF_V1   = 1631488;      // [100][256]
static constexpr size_t OFF_V2   = 1657088;      // [100][256]
static constexpr size_t OFF_CNT  = 1682688;      // barrier counter (u32)

__device__ __forceinline__ float exp2fast(float x){ return __builtin_amdgcn_exp2f(x); }
__device__ __forceinline__ float rcpfast(float x){ return __builtin_amdgcn_rcpf(x); }
__device__ __forceinline__ float sigf(float x){ return rcpfast(1.f + exp2fast(-x*L2E)); }
__device__ __forceinline__ float tanhfast(float x){
  float E = exp2fast(x*K2);            // e^{2x};  inf/0 saturate correctly
  return 1.f - 2.f*rcpfast(E + 1.f);
}
__device__ __forceinline__ unsigned short f2bf(float f){
  unsigned b = __float_as_uint(f);
  return (unsigned short)((b + 0x7FFFu + ((b>>16)&1u))>>16);
}
__device__ __forceinline__ float bf2f(unsigned short u){ return __uint_as_float(((unsigned)u)<<16); }

// epoch barrier across all NWG workgroups (monotonic counter, device scope)
__device__ __forceinline__ void gbar(unsigned* cnt, unsigned target){
  __syncthreads();                               // drains all WG memory ops (vmcnt 0)
  if (threadIdx.x == 0){
    __builtin_amdgcn_fence(__ATOMIC_RELEASE, "agent");
    __hip_atomic_fetch_add(cnt, 1u, __ATOMIC_RELAXED, __HIP_MEMORY_SCOPE_AGENT);
    while (__hip_atomic_load(cnt, __ATOMIC_RELAXED, __HIP_MEMORY_SCOPE_AGENT) < target) {}
    __builtin_amdgcn_fence(__ATOMIC_ACQUIRE, "agent");
  }
  __syncthreads();
}

// ---------------------------------------------------------------------------
// prep kernel: Bc, yG, graw(0), counter init
// ---------------------------------------------------------------------------
__global__ __launch_bounds__(256) void rnn_prep(
    const float* __restrict__ Y, const float* __restrict__ h0,
    const float* __restrict__ outE, const float* __restrict__ W_ih,
    const float* __restrict__ W_hh, const float* __restrict__ b_ih,
    const float* __restrict__ b_hh, const float* __restrict__ att_V,
    const float* __restrict__ att_b, float* __restrict__ ws)
{
  __shared__ float avT[32*257];
  __shared__ float oeL[8*257];
  __shared__ float yL[40];
  __shared__ float h0L[256];
  const int b = blockIdx.x, tid = threadIdx.x;
  float* ws_bc   = ws + OFF_BC;
  float* ws_yg   = ws + OFF_YG;
  float* ws_graw = ws + OFF_GRAW;

  if (b < 256) {                 // Bc[e][h] for 8 e-rows
    int e0 = b*8;
    for (int r=0;r<8;r++) oeL[r*257 + tid] = outE[(size_t)(e0+r)*256 + tid];
    int hl = tid & 31, er = tid >> 5;
    for (int ht=0; ht<8; ++ht) {
      __syncthreads();
      for (int i=0;i<32;i++){ int lin = tid + i*256; int r = lin>>8, j = lin&255;
        avT[r*257 + j] = att_V[(size_t)(ht*32+r)*256 + j]; }
      __syncthreads();
      float acc = 0.f;
      for (int j=0;j<256;j++) acc = fmaf(avT[hl*257 + j], oeL[er*257 + j], acc);
      int h = ht*32 + hl;
      ws_bc[(size_t)(e0+er)*256 + h] = (acc + att_b[h]) * K2;
    }
  } else if (b < 260) {          // yG for 25 timesteps
    int g = b - 256;
    for (int u=0; u<25; ++u) {
      int t = g*25 + u;
      __syncthreads();
      if (tid < 36) yL[tid] = Y[t*36 + tid];
      __syncthreads();
      for (int q=0;q<4;q++){
        int i = tid + 256*q;
        float acc = b_ih[i] + b_hh[i];
        for (int j=0;j<36;j++) acc = fmaf(W_ih[(size_t)i*36 + j], yL[j], acc);
        ws_yg[(size_t)t*1024 + i] = acc;
      }
    }
  } else if (b < 292) {          // graw(0) = yG(0) + W_hh@h0, 32 rows per block
    int s = b - 260;
    if (tid < 256) h0L[tid] = h0[tid];
    if (tid < 36)  yL[tid]  = Y[tid];
    __syncthreads();
    int r = tid>>3, l8 = tid&7;
    int R = s*32 + r;
    float acc = 0.f;
    for (int q=0;q<32;q++){ int j = l8*32 + q; acc = fmaf(W_hh[(size_t)R*256 + j], h0L[j], acc); }
    acc += __shfl_xor(acc,1); acc += __shfl_xor(acc,2); acc += __shfl_xor(acc,4);
    if (l8 == 0){
      float full = acc + b_ih[R] + b_hh[R];
      for (int j=0;j<36;j++) full = fmaf(W_ih[(size_t)R*36 + j], yL[j], full);
      ws_graw[R] = full;
    }
  } else {                       // counter init
    if (tid < 16) ((unsigned*)(ws + OFF_CNT))[tid] = 0u;
  }
}

// ---------------------------------------------------------------------------
// persistent main kernel
// roles: w<32 main (attention e-slice + gates + LSTM), 32..35 MLP1, 36..37 MLP2, 38 MLP3
// ---------------------------------------------------------------------------
__global__ __launch_bounds__(512) void rnn_main(
    const float* __restrict__ c0, const float* __restrict__ outE,
    const float* __restrict__ W_hh, const float* __restrict__ att_W,
    const float* __restrict__ att_vec,
    const float* __restrict__ W1, const float* __restrict__ b1,
    const float* __restrict__ W2, const float* __restrict__ b2,
    const float* __restrict__ W3, const float* __restrict__ b3,
    float* __restrict__ out, float* __restrict__ ws)
{
  __shared__ __align__(16) unsigned char smem[148992];
  const int w = blockIdx.x;
  const int tid = threadIdx.x;

  float* ws_yg   = ws + OFF_YG;
  float* ws_graw = ws + OFF_GRAW;
  float* ws_wsg  = ws + OFF_WSG;
  float* ws_pm   = ws + OFF_PM;
  float* ws_ps   = ws + OFF_PS;
  float* ws_pv   = ws + OFF_PV;
  float* ws_ctxh = ws + OFF_CTXH;
  float* ws_clh  = ws + OFF_CLH;
  float* ws_v1   = ws + OFF_V1;
  float* ws_v2   = ws + OFF_V2;
  unsigned* cnt  = (unsigned*)(ws + OFF_CNT);

  // main-role LDS partitions (byte offsets)
  float*          bcS    = (float*)(smem);                 // [64][264] padded, pre-scaled
  unsigned short* oeS    = (unsigned short*)(smem + 67584);// [64][256] bf16
  float*          whhS   = (float*)(smem + 100352);        // [32][260]
  float*          awS    = (float*)(smem + 133632);        // [8][256]
  float*          wsp    = (float*)(smem + 141824);        // [264] padded WS*K2
  float*          ctxS   = (float*)(smem + 142880);
  float*          clstmS = (float*)(smem + 143904);
  float*          hS     = (float*)(smem + 144928);
  float*          scoreS = (float*)(smem + 145952);        // [64]
  float*          wexpS  = (float*)(smem + 146208);        // [64]
  float*          pS     = (float*)(smem + 146464);        // [512]
  float*          mArr   = (float*)(smem + 148512);        // [32]
  float*          sArr   = (float*)(smem + 148640);
  float*          fArr   = (float*)(smem + 148768);
  // MLP-role partitions
  float* wmS = (float*)(smem);
  float* vbS = nullptr;

  float vh2[32]; float Vpart = 0.f;

  if (w < 32) {
    const float* ws_bc = ws + OFF_BC;
    for (int i=0;i<32;i++){ int lin = tid + i*512; int col = lin>>8, h = lin&255;
      bcS[col*264 + h + (h>>5)] = ws_bc[(size_t)(w*64+col)*256 + h]; }
    for (int i=0;i<32;i++){ int lin = tid + i*512; int col = lin>>8, h = lin&255;
      oeS[col*256 + h] = f2bf(outE[(size_t)(w*64+col)*256 + h]); }
    for (int i=0;i<16;i++){ int lin = tid + i*512; int r = lin>>8, j = lin&255;
      whhS[r*260 + j] = W_hh[(size_t)(w*32+r)*256 + j]; }
    for (int i=0;i<4;i++){ int lin = tid + i*512; int r = lin>>8, j = lin&255;
      awS[r*256 + j] = att_W[(size_t)(w*8+r)*256 + j]; }
    int l8 = tid & 7;
    #pragma unroll
    for (int k=0;k<32;k++){ float vv = att_vec[l8*32 + k]; Vpart += vv; vh2[k] = -2.f*vv; }
  } else if (w < 36) {           // MLP1: 64 rows of W1[256][512]
    vbS = (float*)(smem + 133120);
    int m = w - 32;
    for (int i=0;i<64;i++){ int lin = tid + i*512; int r = lin>>9, k = lin&511;
      wmS[r*520 + k + (k>>6)] = W1[(size_t)(m*64+r)*512 + k]; }
  } else if (w < 38) {           // MLP2: 128 rows of W2[256][256]
    vbS = (float*)(smem + 133120);
    int m = w - 36;
    for (int i=0;i<64;i++){ int lin = tid + i*512; int r = lin>>8, k = lin&255;
      wmS[r*260 + k + (k>>6)] = W2[(size_t)(m*128+r)*256 + k]; }
  } else {                       // MLP3: W3[36][256]
    vbS = (float*)(smem + 37440);
    for (int lin = tid; lin < 36*256; lin += 512){ int r = lin>>8, k = lin&255;
      wmS[r*260 + k + (k>>6)] = W3[(size_t)r*256 + k]; }
  }
  __syncthreads();

  unsigned ep = 0;

  for (int t = 0; t <= 101; ++t) {
    // ================= PHASE A =================
    if (w < 32) {
      if (t <= 100) {
        if (t == 0) {
          if (tid < 256) ctxS[tid] = c0[tid];
        } else {
          // combine attention partials of step t-1 -> ctx(t-1)
          if (tid < 32){ mArr[tid] = ws_pm[(t-1)*32 + tid]; sArr[tid] = ws_ps[(t-1)*32 + tid]; }
          __syncthreads();
          float m = -3.0e38f;
          #pragma unroll
          for (int i=0;i<32;i++) m = fmaxf(m, mArr[i]);
          if (tid < 32) fArr[tid] = exp2fast((mArr[tid]-m)*L2E);
          __syncthreads();
          float stot = 0.f;
          #pragma unroll
          for (int i=0;i<32;i++) stot = fmaf(fArr[i], sArr[i], stot);
          float rs = rcpfast(stot);
          if (tid < 256) {
            const float* pvRow = ws_pv + (size_t)(t-1)*8192 + tid;
            float acc = 0.f;
            #pragma unroll
            for (int i=0;i<32;i++) acc = fmaf(fArr[i], pvRow[i*256], acc);
            float cv = acc * rs;
            ctxS[tid] = cv;
            if (w == 0) { ws_ctxh[(t-1)*256 + tid] = cv; if (t == 100) out[3600 + tid] = cv; }
          }
        }
        __syncthreads();
      }
      if (t <= 99) {
        // LSTM elementwise (c = ctx(t-1)), then WS slice
        if (tid < 256) {
          const float* g = ws_graw + (size_t)t*1024;
          float ig = g[tid], fg = g[256+tid], gg = g[512+tid], og = g[768+tid];
          float c  = ctxS[tid];
          float cl = sigf(fg)*c + sigf(ig)*tanhfast(gg);
          float hn = sigf(og)*tanhfast(cl);
          clstmS[tid] = cl; hS[tid] = hn;
          if (w == 0) ws_clh[t*256 + tid] = cl;
        }
        __syncthreads();
        int r8 = tid >> 6, lane = tid & 63;   // wave r8 computes WS row w*8+r8
        float acc = 0.f;
        #pragma unroll
        for (int q=0;q<4;q++) acc = fmaf(awS[r8*256 + lane + 64*q], hS[lane + 64*q], acc);
        #pragma unroll
        for (int d=1; d<64; d<<=1) acc += __shfl_xor(acc, d);
        if (lane == 0) ws_wsg[t*256 + w*8 + r8] = acc * K2;
      }
    } else if (w >= 36 && w < 38) {
      if (t >= 2) {              // MLP2 for s = t-2
        int s = t - 2;
        if (tid < 256) vbS[tid + (tid>>6)] = ws_v1[s*256 + tid];
        __syncthreads();
        int row = tid >> 2, l4 = tid & 3;
        const float* wr = wmS + row*260 + l4*65;
        const float* vr = vbS + l4*65;
        float acc = 0.f;
        #pragma unroll
        for (int q=0;q<64;q++) acc = fmaf(wr[q], vr[q], acc);
        acc += __shfl_xor(acc,1); acc += __shfl_xor(acc,2);
        if (l4 == 0){ int i = (w-36)*128 + row; ws_v2[s*256 + i] = fmaxf(acc + b2[i], 0.f); }
        __syncthreads();
      }
    }
    ++ep; gbar(cnt, NWG*ep);

    // ================= PHASE B =================
    if (w < 32) {
      if (t <= 99) {
        if (tid < 256){ float v = ws_wsg[t*256 + tid]; wsp[tid + (tid>>5)] = v; }
        __syncthreads();
        // scores for 64 columns: 8 threads/col x 32 h each
        int col = tid >> 3, l8 = tid & 7;
        const float* bcR = bcS + col*264 + l8*33;
        const float* wsR = wsp + l8*33;
        float acc = Vpart;
        #pragma unroll
        for (int k=0;k<32;k++){
          float E = exp2fast(bcR[k] + wsR[k]);     // e^{2x}
          float r = rcpfast(E + 1.f);
          acc = fmaf(vh2[k], r, acc);              // v*(1-2r) summed
        }
        acc += __shfl_xor(acc,1); acc += __shfl_xor(acc,2); acc += __shfl_xor(acc,4);
        if (l8 == 0) scoreS[col] = acc;
        __syncthreads();
        float mw = -3.0e38f;
        #pragma unroll
        for (int i=0;i<64;i++) mw = fmaxf(mw, scoreS[i]);
        if (tid < 64) wexpS[tid] = exp2fast((scoreS[tid]-mw)*L2E);
        __syncthreads();
        { int h = tid & 255, half = tid >> 8;      // partial ctx
          float accp = 0.f;
          #pragma unroll
          for (int i=0;i<32;i++){ int lc = half*32 + i; accp = fmaf(wexpS[lc], bf2f(oeS[lc*256 + h]), accp); }
          pS[half*256 + h] = accp; }
        if (tid == 0){ float sw = 0.f;
          #pragma unroll
          for (int i=0;i<64;i++) sw += wexpS[i];
          ws_ps[t*32 + w] = sw; ws_pm[t*32 + w] = mw; }
        __syncthreads();
        if (tid < 256) ws_pv[(size_t)t*8192 + w*256 + tid] = pS[tid] + pS[256 + tid];
        // gates_raw(t+1) slice: rows w*32..w*32+31
        if (t <= 98) {
          int r32 = tid >> 4, l16 = tid & 15;
          float acc2 = 0.f;
          #pragma unroll
          for (int q=0;q<16;q++){ int j = l16 + 16*q; acc2 = fmaf(whhS[r32*260 + j], hS[j], acc2); }
          acc2 += __shfl_xor(acc2,1); acc2 += __shfl_xor(acc2,2);
          acc2 += __shfl_xor(acc2,4); acc2 += __shfl_xor(acc2,8);
          if (l16 == 0){ int R = w*32 + r32;
            ws_graw[(size_t)(t+1)*1024 + R] = acc2 + ws_yg[(size_t)(t+1)*1024 + R]; }
        }
      }
    } else if (w < 36) {
      if (t >= 1 && t <= 100) {  // MLP1 for s = t-1
        int s = t - 1;
        float val = (tid < 256) ? ws_clh[s*256 + tid] : ws_ctxh[s*256 + (tid-256)];
        vbS[tid + (tid>>6)] = val;
        __syncthreads();
        int row = tid >> 3, l8 = tid & 7;
        const float* wr = wmS + row*520 + l8*65;
        const float* vr = vbS + l8*65;
        float acc = 0.f;
        #pragma unroll
        for (int q=0;q<64;q++) acc = fmaf(wr[q], vr[q], acc);
        acc += __shfl_xor(acc,1); acc += __shfl_xor(acc,2); acc += __shfl_xor(acc,4);
        if (l8 == 0){ int i = (w-32)*64 + row; ws_v1[s*256 + i] = fmaxf(acc + b1[i], 0.f); }
        __syncthreads();
      }
    } else if (w == 38) {
      if (t >= 2) {              // MLP3 for s = t-2 -> output
        int s = t - 2;
        if (tid < 256) vbS[tid + (tid>>6)] = ws_v2[s*256 + tid];
        __syncthreads();
        if (tid < 288) {
          int row = tid >> 3, l8 = tid & 7;
          int kb = l8*32;
          const float* wr = wmS + row*260 + kb + (kb>>6);
          const float* vr = vbS + kb + (kb>>6);
          float acc = 0.f;
          #pragma unroll
          for (int q=0;q<32;q++) acc = fmaf(wr[q], vr[q], acc);
          acc += __shfl_xor(acc,1); acc += __shfl_xor(acc,2); acc += __shfl_xor(acc,4);
          if (l8 == 0) out[s*36 + row] = acc + b3[row];
        }
        __syncthreads();
      }
    }
    ++ep; gbar(cnt, NWG*ep);
  }
}

// ---------------------------------------------------------------------------
extern "C" void kernel_launch(void* const* d_in, const int* in_sizes, int n_in,
                              void* d_out, int out_size, void* d_ws, size_t ws_size,
                              hipStream_t stream) {
  (void)in_sizes; (void)n_in; (void)out_size; (void)ws_size;
  const float* Y       = (const float*)d_in[0];
  const float* h0      = (const float*)d_in[1];
  const float* c0      = (const float*)d_in[2];
  const float* outEnc  = (const float*)d_in[3];
  const float* W_ih    = (const float*)d_in[4];
  const float* W_hh    = (const float*)d_in[5];
  const float* b_ih    = (const float*)d_in[6];
  const float* b_hh    = (const float*)d_in[7];
  const float* att_W   = (const float*)d_in[8];
  const float* att_V   = (const float*)d_in[9];
  const float* att_b   = (const float*)d_in[10];
  const float* att_vec = (const float*)d_in[11];
  const float* W1      = (const float*)d_in[12];
  const float* b1      = (const float*)d_in[13];
  const float* W2      = (const float*)d_in[14];
  const float* b2      = (const float*)d_in[15];
  const float* W3      = (const float*)d_in[16];
  const float* b3      = (const float*)d_in[17];
  float* out = (float*)d_out;
  float* ws  = (float*)d_ws;

  rnn_prep<<<dim3(293), dim3(256), 0, stream>>>(Y, h0, outEnc, W_ih, W_hh, b_ih, b_hh,
                                                att_V, att_b, ws);
  rnn_main<<<dim3(39), dim3(512), 0, stream>>>(c0, outEnc, W_hh, att_W, att_vec,
                                               W1, b1, W2, b2, W3, b3, out, ws);
}

// Round 3
// 1043.762 us; speedup vs baseline: 1.7736x; 1.7736x over previous
//
#include <hip/hip_runtime.h>
#include <stdint.h>

// ---------------------------------------------------------------------------
// DecoderRNN: 100-step LSTM + additive attention + 3-layer MLP, B=1.
// R3 = R2 (fence-free sync via relaxed agent-scope sc1 atomics) + bounded
// spin-waits so a sync bug can never wedge the container.
// ---------------------------------------------------------------------------

static constexpr int      NB  = 32;              // barrier participants (main WGs)
static constexpr float    L2E = 1.44269504088896341f;   // log2(e)
static constexpr float    K2  = 2.88539008177792681f;   // 2*log2(e)
static constexpr unsigned SPIN_LIMIT = 200000u;  // ~20-30 ms; legit waits are <10 us

// workspace layout (float offsets)
static constexpr size_t OFF_BC   = 0;            // [2048][256] (VOut+att_b)*K2
static constexpr size_t OFF_YG   = 524288;       // [100][1024] y@W_ih.T + b_ih + b_hh
static constexpr size_t OFF_GRAW = 626688;       // [100][1024] full gate preacts
static constexpr size_t OFF_WSG  = 729088;       // [100][256]  WS*K2
static constexpr size_t OFF_PM   = 754688;       // [100][32]   per-WG score max
static constexpr size_t OFF_PS   = 757888;       // [100][32]   per-WG exp-sum
static constexpr size_t OFF_PV   = 761088;       // [100][32][256] per-WG partial ctx
static constexpr size_t OFF_CTXH = 1580288;      // [100][256] ctx history
static constexpr size_t OFF_CLH  = 1605888;      // [100][256] cLSTM history
static constexpr size_t OFF_V1   = 1631488;      // [100][256]
static constexpr size_t OFF_V2   = 1657088;      // [100][256]
static constexpr size_t OFF_CNT  = 1682688;      // u32: [0]=barrier cnt, [16..115]=fv1, [128..227]=fv2

__device__ __forceinline__ float exp2fast(float x){ return __builtin_amdgcn_exp2f(x); }
__device__ __forceinline__ float rcpfast(float x){ return __builtin_amdgcn_rcpf(x); }
__device__ __forceinline__ float sigf(float x){ return rcpfast(1.f + exp2fast(-x*L2E)); }
__device__ __forceinline__ float tanhfast(float x){
  float E = exp2fast(x*K2);            // e^{2x};  inf/0 saturate correctly
  return 1.f - 2.f*rcpfast(E + 1.f);
}
__device__ __forceinline__ unsigned short f2bf(float f){
  unsigned b = __float_as_uint(f);
  return (unsigned short)((b + 0x7FFFu + ((b>>16)&1u))>>16);
}
__device__ __forceinline__ float bf2f(unsigned short u){ return __uint_as_float(((unsigned)u)<<16); }

// relaxed agent-scope accesses: sc1-flagged -> coherent at Infinity Cache,
// bypassing the (non-cross-coherent) per-XCD L2s. No wbl2/inv fences needed.
__device__ __forceinline__ void gstore(float* p, float v){
  __hip_atomic_store(p, v, __ATOMIC_RELAXED, __HIP_MEMORY_SCOPE_AGENT);
}
__device__ __forceinline__ float gload(const float* p){
  return __hip_atomic_load(p, __ATOMIC_RELAXED, __HIP_MEMORY_SCOPE_AGENT);
}

// barrier pieces: arrive = drain own stores -> WG barrier -> one atomic add.
__device__ __forceinline__ void bar_arrive(unsigned* cnt){
  asm volatile("s_waitcnt vmcnt(0)" ::: "memory");   // own sc1 stores complete at IC
  __syncthreads();                                   // all threads in WG drained
  if (threadIdx.x == 0)
    __hip_atomic_fetch_add(cnt, 1u, __ATOMIC_RELAXED, __HIP_MEMORY_SCOPE_AGENT);
}
__device__ __forceinline__ void bar_wait(unsigned* cnt, unsigned target){
  if (threadIdx.x == 0){
    unsigned it = 0;
    while (__hip_atomic_load(cnt, __ATOMIC_RELAXED, __HIP_MEMORY_SCOPE_AGENT) < target)
      if (++it > SPIN_LIMIT) break;                  // safety: never wedge the GPU
  }
  __syncthreads();
}
__device__ __forceinline__ void poll_ge(unsigned* p, unsigned tgt){
  if (threadIdx.x == 0){
    unsigned it = 0;
    while (__hip_atomic_load(p, __ATOMIC_RELAXED, __HIP_MEMORY_SCOPE_AGENT) < tgt){
      __builtin_amdgcn_s_sleep(1);                   // off critical path; be polite
      if (++it > SPIN_LIMIT) break;                  // safety: never wedge the GPU
    }
  }
  __syncthreads();
}

// ---------------------------------------------------------------------------
// prep kernel: Bc, yG, graw(0), counter/flag init
// ---------------------------------------------------------------------------
__global__ __launch_bounds__(256) void rnn_prep(
    const float* __restrict__ Y, const float* __restrict__ h0,
    const float* __restrict__ outE, const float* __restrict__ W_ih,
    const float* __restrict__ W_hh, const float* __restrict__ b_ih,
    const float* __restrict__ b_hh, const float* __restrict__ att_V,
    const float* __restrict__ att_b, float* __restrict__ ws)
{
  __shared__ float avT[32*257];
  __shared__ float oeL[8*257];
  __shared__ float yL[40];
  __shared__ float h0L[256];
  const int b = blockIdx.x, tid = threadIdx.x;
  float* ws_bc   = ws + OFF_BC;
  float* ws_yg   = ws + OFF_YG;
  float* ws_graw = ws + OFF_GRAW;

  if (b < 256) {                 // Bc[e][h] for 8 e-rows
    int e0 = b*8;
    for (int r=0;r<8;r++) oeL[r*257 + tid] = outE[(size_t)(e0+r)*256 + tid];
    int hl = tid & 31, er = tid >> 5;
    for (int ht=0; ht<8; ++ht) {
      __syncthreads();
      for (int i=0;i<32;i++){ int lin = tid + i*256; int r = lin>>8, j = lin&255;
        avT[r*257 + j] = att_V[(size_t)(ht*32+r)*256 + j]; }
      __syncthreads();
      float acc = 0.f;
      for (int j=0;j<256;j++) acc = fmaf(avT[hl*257 + j], oeL[er*257 + j], acc);
      int h = ht*32 + hl;
      ws_bc[(size_t)(e0+er)*256 + h] = (acc + att_b[h]) * K2;
    }
  } else if (b < 260) {          // yG for 25 timesteps
    int g = b - 256;
    for (int u=0; u<25; ++u) {
      int t = g*25 + u;
      __syncthreads();
      if (tid < 36) yL[tid] = Y[t*36 + tid];
      __syncthreads();
      for (int q=0;q<4;q++){
        int i = tid + 256*q;
        float acc = b_ih[i] + b_hh[i];
        for (int j=0;j<36;j++) acc = fmaf(W_ih[(size_t)i*36 + j], yL[j], acc);
        ws_yg[(size_t)t*1024 + i] = acc;
      }
    }
  } else if (b < 292) {          // graw(0) = yG(0) + W_hh@h0, 32 rows per block
    int s = b - 260;
    if (tid < 256) h0L[tid] = h0[tid];
    if (tid < 36)  yL[tid]  = Y[tid];
    __syncthreads();
    int r = tid>>3, l8 = tid&7;
    int R = s*32 + r;
    float acc = 0.f;
    for (int q=0;q<32;q++){ int j = l8*32 + q; acc = fmaf(W_hh[(size_t)R*256 + j], h0L[j], acc); }
    acc += __shfl_xor(acc,1); acc += __shfl_xor(acc,2); acc += __shfl_xor(acc,4);
    if (l8 == 0){
      float full = acc + b_ih[R] + b_hh[R];
      for (int j=0;j<36;j++) full = fmaf(W_ih[(size_t)R*36 + j], yL[j], full);
      ws_graw[R] = full;
    }
  } else {                       // counter + flag init (256 u32s covers all)
    ((unsigned*)(ws + OFF_CNT))[tid] = 0u;
  }
}

// ---------------------------------------------------------------------------
// persistent main kernel
// roles: w<32 main (attention e-slice + gates + LSTM), 32..35 MLP1, 36..37 MLP2, 38 MLP3
// ---------------------------------------------------------------------------
__global__ __launch_bounds__(512) void rnn_main(
    const float* __restrict__ c0, const float* __restrict__ outE,
    const float* __restrict__ W_hh, const float* __restrict__ att_W,
    const float* __restrict__ att_vec,
    const float* __restrict__ W1, const float* __restrict__ b1,
    const float* __restrict__ W2, const float* __restrict__ b2,
    const float* __restrict__ W3, const float* __restrict__ b3,
    float* __restrict__ out, float* __restrict__ ws)
{
  __shared__ __align__(16) unsigned char smem[148992];
  const int w = blockIdx.x;
  const int tid = threadIdx.x;

  float* ws_yg   = ws + OFF_YG;
  float* ws_graw = ws + OFF_GRAW;
  float* ws_wsg  = ws + OFF_WSG;
  float* ws_pm   = ws + OFF_PM;
  float* ws_ps   = ws + OFF_PS;
  float* ws_pv   = ws + OFF_PV;
  float* ws_ctxh = ws + OFF_CTXH;
  float* ws_clh  = ws + OFF_CLH;
  float* ws_v1   = ws + OFF_V1;
  float* ws_v2   = ws + OFF_V2;
  unsigned* cnt  = (unsigned*)(ws + OFF_CNT);
  unsigned* fv1  = cnt + 16;     // [100]
  unsigned* fv2  = cnt + 128;    // [100]

  // main-role LDS partitions (byte offsets)
  float*          bcS    = (float*)(smem);                 // [64][264] padded, pre-scaled
  unsigned short* oeS    = (unsigned short*)(smem + 67584);// [64][256] bf16
  float*          whhS   = (float*)(smem + 100352);        // [32][260]
  float*          awS    = (float*)(smem + 133632);        // [8][256]
  float*          wsp    = (float*)(smem + 141824);        // [264] padded WS*K2
  float*          ctxS   = (float*)(smem + 142880);
  float*          clstmS = (float*)(smem + 143904);
  float*          hS     = (float*)(smem + 144928);
  float*          scoreS = (float*)(smem + 145952);        // [64]
  float*          wexpS  = (float*)(smem + 146208);        // [64]
  float*          pS     = (float*)(smem + 146464);        // [512]
  float*          mArr   = (float*)(smem + 148512);        // [32]
  float*          sArr   = (float*)(smem + 148640);
  float*          fArr   = (float*)(smem + 148768);
  // MLP-role partitions
  float* wmS = (float*)(smem);

  if (w < 32) {
    float vh2[32]; float Vpart = 0.f;
    const float* ws_bc = ws + OFF_BC;
    for (int i=0;i<32;i++){ int lin = tid + i*512; int col = lin>>8, h = lin&255;
      bcS[col*264 + h + (h>>5)] = ws_bc[(size_t)(w*64+col)*256 + h]; }
    for (int i=0;i<32;i++){ int lin = tid + i*512; int col = lin>>8, h = lin&255;
      oeS[col*256 + h] = f2bf(outE[(size_t)(w*64+col)*256 + h]); }
    for (int i=0;i<16;i++){ int lin = tid + i*512; int r = lin>>8, j = lin&255;
      whhS[r*260 + j] = W_hh[(size_t)(w*32+r)*256 + j]; }
    for (int i=0;i<4;i++){ int lin = tid + i*512; int r = lin>>8, j = lin&255;
      awS[r*256 + j] = att_W[(size_t)(w*8+r)*256 + j]; }
    { int l8 = tid & 7;
      #pragma unroll
      for (int k=0;k<32;k++){ float vv = att_vec[l8*32 + k]; Vpart += vv; vh2[k] = -2.f*vv; } }
    __syncthreads();

    unsigned ep = 0;
    for (int t = 0; t <= 100; ++t) {
      // ================= PHASE A =================
      if (t == 0) {
        if (tid < 256) ctxS[tid] = c0[tid];
      } else {
        // combine attention partials of step t-1 -> ctx(t-1)
        if (tid < 32){ mArr[tid] = gload(&ws_pm[(t-1)*32 + tid]);
                       sArr[tid] = gload(&ws_ps[(t-1)*32 + tid]); }
        __syncthreads();
        float m = -3.0e38f;
        #pragma unroll
        for (int i=0;i<32;i++) m = fmaxf(m, mArr[i]);
        if (tid < 32) fArr[tid] = exp2fast((mArr[tid]-m)*L2E);
        __syncthreads();
        float stot = 0.f;
        #pragma unroll
        for (int i=0;i<32;i++) stot = fmaf(fArr[i], sArr[i], stot);
        float rs = rcpfast(stot);
        if (tid < 256) {
          const float* pvRow = ws_pv + (size_t)(t-1)*8192 + tid;
          float pv[32];
          #pragma unroll
          for (int i=0;i<32;i++) pv[i] = gload(&pvRow[i*256]);  // pipelined IC loads
          float acc = 0.f;
          #pragma unroll
          for (int i=0;i<32;i++) acc = fmaf(fArr[i], pv[i], acc);
          float cv = acc * rs;
          ctxS[tid] = cv;
          if (w == 0) { gstore(&ws_ctxh[(t-1)*256 + tid], cv);
                        if (t == 100) out[3600 + tid] = cv; }
        }
      }
      __syncthreads();
      if (t <= 99) {
        // LSTM elementwise (c = ctx(t-1)), then WS slice
        if (tid < 256) {
          const float* g = ws_graw + (size_t)t*1024;
          float ig = gload(&g[tid]),     fg = gload(&g[256+tid]);
          float gg = gload(&g[512+tid]), og = gload(&g[768+tid]);
          float c  = ctxS[tid];
          float cl = sigf(fg)*c + sigf(ig)*tanhfast(gg);
          float hn = sigf(og)*tanhfast(cl);
          clstmS[tid] = cl; hS[tid] = hn;
          if (w == 0) gstore(&ws_clh[t*256 + tid], cl);
        }
        __syncthreads();
        int r8 = tid >> 6, lane = tid & 63;   // wave r8 computes WS row w*8+r8
        float acc = 0.f;
        #pragma unroll
        for (int q=0;q<4;q++) acc = fmaf(awS[r8*256 + lane + 64*q], hS[lane + 64*q], acc);
        #pragma unroll
        for (int d=1; d<64; d<<=1) acc += __shfl_xor(acc, d);
        if (lane == 0) gstore(&ws_wsg[t*256 + w*8 + r8], acc * K2);
      }
      ++ep;
      bar_arrive(cnt);
      if (t == 100) break;                    // last arrive releases MLP1 s=99
      bar_wait(cnt, NB*ep);

      // ================= PHASE B ================= (t <= 99 here)
      if (tid < 256){ float v = gload(&ws_wsg[t*256 + tid]); wsp[tid + (tid>>5)] = v; }
      __syncthreads();
      // scores for 64 columns: 8 threads/col x 32 h each
      { int col = tid >> 3, l8 = tid & 7;
        const float* bcR = bcS + col*264 + l8*33;
        const float* wsR = wsp + l8*33;
        float acc = Vpart;
        #pragma unroll
        for (int k=0;k<32;k++){
          float E = exp2fast(bcR[k] + wsR[k]);     // e^{2x}
          float r = rcpfast(E + 1.f);
          acc = fmaf(vh2[k], r, acc);              // v*(1-2r) summed
        }
        acc += __shfl_xor(acc,1); acc += __shfl_xor(acc,2); acc += __shfl_xor(acc,4);
        if (l8 == 0) scoreS[col] = acc; }
      __syncthreads();
      { float mw = -3.0e38f;
        #pragma unroll
        for (int i=0;i<64;i++) mw = fmaxf(mw, scoreS[i]);
        if (tid < 64) wexpS[tid] = exp2fast((scoreS[tid]-mw)*L2E);
        __syncthreads();
        { int h = tid & 255, half = tid >> 8;      // partial ctx
          float accp = 0.f;
          #pragma unroll
          for (int i=0;i<32;i++){ int lc = half*32 + i; accp = fmaf(wexpS[lc], bf2f(oeS[lc*256 + h]), accp); }
          pS[half*256 + h] = accp; }
        if (tid == 0){ float sw = 0.f;
          #pragma unroll
          for (int i=0;i<64;i++) sw += wexpS[i];
          gstore(&ws_ps[t*32 + w], sw); gstore(&ws_pm[t*32 + w], mw); } }
      __syncthreads();
      if (tid < 256) gstore(&ws_pv[(size_t)t*8192 + w*256 + tid], pS[tid] + pS[256 + tid]);
      // gates_raw(t+1) slice: rows w*32..w*32+31
      if (t <= 98) {
        int r32 = tid >> 4, l16 = tid & 15;
        float acc2 = 0.f;
        #pragma unroll
        for (int q=0;q<16;q++){ int j = l16 + 16*q; acc2 = fmaf(whhS[r32*260 + j], hS[j], acc2); }
        acc2 += __shfl_xor(acc2,1); acc2 += __shfl_xor(acc2,2);
        acc2 += __shfl_xor(acc2,4); acc2 += __shfl_xor(acc2,8);
        if (l16 == 0){ int R = w*32 + r32;
          gstore(&ws_graw[(size_t)(t+1)*1024 + R],
                 acc2 + ws_yg[(size_t)(t+1)*1024 + R]); }
      }
      ++ep;
      bar_arrive(cnt);
      bar_wait(cnt, NB*ep);
    }
  } else if (w < 36) {           // ---------------- MLP1: 64 rows of W1[256][512]
    float* vbS = (float*)(smem + 133120);
    int m = w - 32;
    for (int i=0;i<64;i++){ int lin = tid + i*512; int r = lin>>9, k = lin&511;
      wmS[r*520 + k + (k>>6)] = W1[(size_t)(m*64+r)*512 + k]; }
    __syncthreads();
    for (int s=0; s<100; ++s){
      poll_ge(cnt, (unsigned)NB*(2u*s+3u));        // clh[s] (ep 2s+1) + ctxh[s] (ep 2s+3)
      { float val = (tid < 256) ? gload(&ws_clh[s*256 + tid])
                                : gload(&ws_ctxh[s*256 + (tid-256)]);
        vbS[tid + (tid>>6)] = val; }
      __syncthreads();
      int row = tid >> 3, l8 = tid & 7;
      const float* wr = wmS + row*520 + l8*65;
      const float* vr = vbS + l8*65;
      float acc = 0.f;
      #pragma unroll
      for (int q=0;q<64;q++) acc = fmaf(wr[q], vr[q], acc);
      acc += __shfl_xor(acc,1); acc += __shfl_xor(acc,2); acc += __shfl_xor(acc,4);
      if (l8 == 0){ int i = m*64 + row; gstore(&ws_v1[s*256 + i], fmaxf(acc + b1[i], 0.f)); }
      bar_arrive(&fv1[s]);                          // drain + flag
    }
  } else if (w < 38) {           // ---------------- MLP2: 128 rows of W2[256][256]
    float* vbS = (float*)(smem + 133120);
    int m = w - 36;
    for (int i=0;i<64;i++){ int lin = tid + i*512; int r = lin>>8, k = lin&255;
      wmS[r*260 + k + (k>>6)] = W2[(size_t)(m*128+r)*256 + k]; }
    __syncthreads();
    for (int s=0; s<100; ++s){
      poll_ge(&fv1[s], 4u);
      if (tid < 256) vbS[tid + (tid>>6)] = gload(&ws_v1[s*256 + tid]);
      __syncthreads();
      int row = tid >> 2, l4 = tid & 3;
      const float* wr = wmS + row*260 + l4*65;
      const float* vr = vbS + l4*65;
      float acc = 0.f;
      #pragma unroll
      for (int q=0;q<64;q++) acc = fmaf(wr[q], vr[q], acc);
      acc += __shfl_xor(acc,1); acc += __shfl_xor(acc,2);
      if (l4 == 0){ int i = m*128 + row; gstore(&ws_v2[s*256 + i], fmaxf(acc + b2[i], 0.f)); }
      bar_arrive(&fv2[s]);
    }
  } else {                       // ---------------- MLP3: W3[36][256] -> out
    float* vbS = (float*)(smem + 37440);
    for (int lin = tid; lin < 36*256; lin += 512){ int r = lin>>8, k = lin&255;
      wmS[r*260 + k + (k>>6)] = W3[(size_t)r*256 + k]; }
    __syncthreads();
    for (int s=0; s<100; ++s){
      poll_ge(&fv2[s], 2u);
      if (tid < 256) vbS[tid + (tid>>6)] = gload(&ws_v2[s*256 + tid]);
      __syncthreads();
      if (tid < 288) {
        int row = tid >> 3, l8 = tid & 7;
        int kb = l8*32;
        const float* wr = wmS + row*260 + kb + (kb>>6);
        const float* vr = vbS + kb + (kb>>6);
        float acc = 0.f;
        #pragma unroll
        for (int q=0;q<32;q++) acc = fmaf(wr[q], vr[q], acc);
        acc += __shfl_xor(acc,1); acc += __shfl_xor(acc,2); acc += __shfl_xor(acc,4);
        if (l8 == 0) out[s*36 + row] = acc + b3[row];   // host-visible after kernel end
      }
      __syncthreads();
    }
  }
}

// ---------------------------------------------------------------------------
extern "C" void kernel_launch(void* const* d_in, const int* in_sizes, int n_in,
                              void* d_out, int out_size, void* d_ws, size_t ws_size,
                              hipStream_t stream) {
  (void)in_sizes; (void)n_in; (void)out_size; (void)ws_size;
  const float* Y       = (const float*)d_in[0];
  const float* h0      = (const float*)d_in[1];
  const float* c0      = (const float*)d_in[2];
  const float* outEnc  = (const float*)d_in[3];
  const float* W_ih    = (const float*)d_in[4];
  const float* W_hh    = (const float*)d_in[5];
  const float* b_ih    = (const float*)d_in[6];
  const float* b_hh    = (const float*)d_in[7];
  const float* att_W   = (const float*)d_in[8];
  const float* att_V   = (const float*)d_in[9];
  const float* att_b   = (const float*)d_in[10];
  const float* att_vec = (const float*)d_in[11];
  const float* W1      = (const float*)d_in[12];
  const float* b1      = (const float*)d_in[13];
  const float* W2      = (const float*)d_in[14];
  const float* b2      = (const float*)d_in[15];
  const float* W3      = (const float*)d_in[16];
  const float* b3      = (const float*)d_in[17];
  float* out = (float*)d_out;
  float* ws  = (float*)d_ws;

  rnn_prep<<<dim3(293), dim3(256), 0, stream>>>(Y, h0, outEnc, W_ih, W_hh, b_ih, b_hh,
                                                att_V, att_b, ws);
  rnn_main<<<dim3(39), dim3(512), 0, stream>>>(c0, outEnc, W_hh, att_W, att_vec,
                                               W1, b1, W2, b2, W3, b3, out, ws);
}

// Round 4
// 722.492 us; speedup vs baseline: 2.5623x; 1.4447x over previous
//
#include <hip/hip_runtime.h>
#include <stdint.h>

// ---------------------------------------------------------------------------
// DecoderRNN: 100-step LSTM + additive attention + 3-layer MLP, B=1.
// R4: ONE global barrier per step.
//  - no-max softmax; partials accumulated via float atomicAdd into ctx_raw/s_tot
//  - att_W held in registers (128/thread) -> WS computed fully per-WG, no handoff
//  - flag-array barrier (no contended atomic counter on critical path)
// All cross-WG data via relaxed agent-scope (sc1) atomics -> Infinity Cache.
// ---------------------------------------------------------------------------

static constexpr float    L2E = 1.44269504088896341f;   // log2(e)
static constexpr float    K2  = 2.88539008177792681f;   // 2*log2(e)
static constexpr unsigned SPIN_LIMIT = 200000u;  // safety: never wedge the GPU

// workspace layout (float offsets)
static constexpr size_t OFF_BC   = 0;            // [2048][256] (VOut+att_b)*K2
static constexpr size_t OFF_YG   = 524288;       // [100][1024] y@W_ih.T + b_ih + b_hh
static constexpr size_t OFF_GRAW = 626688;       // [100][1024] full gate preacts
static constexpr size_t OFF_CRAW = 729088;       // [100][256] unnormalized ctx accum
static constexpr size_t OFF_STOT = 754688;       // [100] softmax denom accum (+pad to 128)
static constexpr size_t OFF_CLH  = 754816;       // [100][256] cLSTM history
static constexpr size_t OFF_V1   = 780416;       // [100][256]
static constexpr size_t OFF_V2   = 806016;       // [100][256]
static constexpr size_t OFF_SYNC = 831616;       // u32[512]: flags[64] | fv1@64[100] | fv2@192[100]

__device__ __forceinline__ float exp2fast(float x){ return __builtin_amdgcn_exp2f(x); }
__device__ __forceinline__ float rcpfast(float x){ return __builtin_amdgcn_rcpf(x); }
__device__ __forceinline__ float sigf(float x){ return rcpfast(1.f + exp2fast(-x*L2E)); }
__device__ __forceinline__ float tanhfast(float x){
  float E = exp2fast(x*K2);            // e^{2x}; inf/0 saturate correctly
  return 1.f - 2.f*rcpfast(E + 1.f);
}
__device__ __forceinline__ unsigned short f2bf(float f){
  unsigned b = __float_as_uint(f);
  return (unsigned short)((b + 0x7FFFu + ((b>>16)&1u))>>16);
}
__device__ __forceinline__ float bf2f(unsigned short u){ return __uint_as_float(((unsigned)u)<<16); }

// relaxed agent-scope (sc1) accesses: coherent at Infinity Cache, bypass XCD L2s
__device__ __forceinline__ void gstore(float* p, float v){
  __hip_atomic_store(p, v, __ATOMIC_RELAXED, __HIP_MEMORY_SCOPE_AGENT);
}
__device__ __forceinline__ float gload(const float* p){
  return __hip_atomic_load(p, __ATOMIC_RELAXED, __HIP_MEMORY_SCOPE_AGENT);
}
__device__ __forceinline__ void gstore_u32(unsigned* p, unsigned v){
  __hip_atomic_store(p, v, __ATOMIC_RELAXED, __HIP_MEMORY_SCOPE_AGENT);
}
__device__ __forceinline__ unsigned gload_u32(const unsigned* p){
  return __hip_atomic_load(p, __ATOMIC_RELAXED, __HIP_MEMORY_SCOPE_AGENT);
}
__device__ __forceinline__ void gatomic_addf(float* p, float v){
  (void)__hip_atomic_fetch_add(p, v, __ATOMIC_RELAXED, __HIP_MEMORY_SCOPE_AGENT);
}

// flag-array barrier: each WG writes its slot; wave0 polls all 32 slots.
__device__ __forceinline__ void fbar(unsigned* flags, int w, unsigned ep){
  asm volatile("s_waitcnt vmcnt(0)" ::: "memory");   // own sc1 stores/atomics done at IC
  __syncthreads();
  if (threadIdx.x == 0) gstore_u32(&flags[w], ep);
  if (threadIdx.x < 64) {
    int lane = threadIdx.x;
    unsigned it = 0;
    for (;;) {
      unsigned v = (lane < 32) ? gload_u32(&flags[lane]) : ep;
      if (__all((int)(v >= ep))) break;
      if (++it > SPIN_LIMIT) break;                  // safety
    }
  }
  __syncthreads();
}
// same wait, polite (MLP consumers)
__device__ __forceinline__ void fwait_sleep(unsigned* flags, unsigned ep){
  if (threadIdx.x < 64) {
    int lane = threadIdx.x;
    unsigned it = 0;
    for (;;) {
      unsigned v = (lane < 32) ? gload_u32(&flags[lane]) : ep;
      if (__all((int)(v >= ep))) break;
      __builtin_amdgcn_s_sleep(2);
      if (++it > SPIN_LIMIT) break;
    }
  }
  __syncthreads();
}
// MLP chain: small atomic counters (off critical path)
__device__ __forceinline__ void arrive_cnt(unsigned* cnt){
  asm volatile("s_waitcnt vmcnt(0)" ::: "memory");
  __syncthreads();
  if (threadIdx.x == 0)
    __hip_atomic_fetch_add(cnt, 1u, __ATOMIC_RELAXED, __HIP_MEMORY_SCOPE_AGENT);
}
__device__ __forceinline__ void poll_ge(unsigned* p, unsigned tgt){
  if (threadIdx.x == 0){
    unsigned it = 0;
    while (gload_u32(p) < tgt){
      __builtin_amdgcn_s_sleep(2);
      if (++it > SPIN_LIMIT) break;
    }
  }
  __syncthreads();
}

// ---------------------------------------------------------------------------
// prep kernel: Bc, yG, graw(0), zero ctx_raw/s_tot/sync
// ---------------------------------------------------------------------------
__global__ __launch_bounds__(256) void rnn_prep(
    const float* __restrict__ Y, const float* __restrict__ h0,
    const float* __restrict__ outE, const float* __restrict__ W_ih,
    const float* __restrict__ W_hh, const float* __restrict__ b_ih,
    const float* __restrict__ b_hh, const float* __restrict__ att_V,
    const float* __restrict__ att_b, float* __restrict__ ws)
{
  __shared__ float avT[32*257];
  __shared__ float oeL[8*257];
  __shared__ float yL[40];
  __shared__ float h0L[256];
  const int b = blockIdx.x, tid = threadIdx.x;
  float* ws_bc   = ws + OFF_BC;
  float* ws_yg   = ws + OFF_YG;
  float* ws_graw = ws + OFF_GRAW;

  if (b < 256) {                 // Bc[e][h] for 8 e-rows
    int e0 = b*8;
    for (int r=0;r<8;r++) oeL[r*257 + tid] = outE[(size_t)(e0+r)*256 + tid];
    int hl = tid & 31, er = tid >> 5;
    for (int ht=0; ht<8; ++ht) {
      __syncthreads();
      for (int i=0;i<32;i++){ int lin = tid + i*256; int r = lin>>8, j = lin&255;
        avT[r*257 + j] = att_V[(size_t)(ht*32+r)*256 + j]; }
      __syncthreads();
      float acc = 0.f;
      for (int j=0;j<256;j++) acc = fmaf(avT[hl*257 + j], oeL[er*257 + j], acc);
      int h = ht*32 + hl;
      ws_bc[(size_t)(e0+er)*256 + h] = (acc + att_b[h]) * K2;
    }
  } else if (b < 260) {          // yG for 25 timesteps
    int g = b - 256;
    for (int u=0; u<25; ++u) {
      int t = g*25 + u;
      __syncthreads();
      if (tid < 36) yL[tid] = Y[t*36 + tid];
      __syncthreads();
      for (int q=0;q<4;q++){
        int i = tid + 256*q;
        float acc = b_ih[i] + b_hh[i];
        for (int j=0;j<36;j++) acc = fmaf(W_ih[(size_t)i*36 + j], yL[j], acc);
        ws_yg[(size_t)t*1024 + i] = acc;
      }
    }
  } else if (b < 292) {          // graw(0) = yG(0) + W_hh@h0, 32 rows per block
    int s = b - 260;
    if (tid < 256) h0L[tid] = h0[tid];
    if (tid < 36)  yL[tid]  = Y[tid];
    __syncthreads();
    int r = tid>>3, l8 = tid&7;
    int R = s*32 + r;
    float acc = 0.f;
    for (int q=0;q<32;q++){ int j = l8*32 + q; acc = fmaf(W_hh[(size_t)R*256 + j], h0L[j], acc); }
    acc += __shfl_xor(acc,1); acc += __shfl_xor(acc,2); acc += __shfl_xor(acc,4);
    if (l8 == 0){
      float full = acc + b_ih[R] + b_hh[R];
      for (int j=0;j<36;j++) full = fmaf(W_ih[(size_t)R*36 + j], yL[j], full);
      ws_graw[R] = full;
    }
  } else if (b == 292) {         // zero sync region (512 u32)
    unsigned* s0 = (unsigned*)(ws + OFF_SYNC);
    s0[tid] = 0u; s0[tid + 256] = 0u;
  } else if (b == 293) {         // zero s_tot
    if (tid < 128) ws[OFF_STOT + tid] = 0.f;
  } else {                       // b in [294, 394): zero ctx_raw[t]
    int t = b - 294;
    ws[OFF_CRAW + (size_t)t*256 + tid] = 0.f;
  }
}

// ---------------------------------------------------------------------------
// persistent main kernel
// roles: w<32 main (attention e-slice + LSTM + gates), 32..35 MLP1, 36..37 MLP2, 38 MLP3
// ---------------------------------------------------------------------------
__global__ __launch_bounds__(512, 2) void rnn_main(
    const float* __restrict__ c0, const float* __restrict__ outE,
    const float* __restrict__ W_hh, const float* __restrict__ att_W,
    const float* __restrict__ att_vec,
    const float* __restrict__ W1, const float* __restrict__ b1,
    const float* __restrict__ W2, const float* __restrict__ b2,
    const float* __restrict__ W3, const float* __restrict__ b3,
    float* __restrict__ out, float* __restrict__ ws)
{
  __shared__ __align__(16) unsigned char smem[140288];
  const int w = blockIdx.x;
  const int tid = threadIdx.x;

  float* ws_yg   = ws + OFF_YG;
  float* ws_graw = ws + OFF_GRAW;
  float* ws_craw = ws + OFF_CRAW;
  float* ws_stot = ws + OFF_STOT;
  float* ws_clh  = ws + OFF_CLH;
  float* ws_v1   = ws + OFF_V1;
  float* ws_v2   = ws + OFF_V2;
  unsigned* flags = (unsigned*)(ws + OFF_SYNC);        // [32] (64 slots reserved)
  unsigned* fv1   = flags + 64;                        // [100]
  unsigned* fv2   = flags + 192;                       // [100]

  if (w < 32) {
    // ---------------- main role ----------------
    float*          bcS    = (float*)(smem);                 // [64][264] padded, *K2
    unsigned short* oeS    = (unsigned short*)(smem + 67584);// [64][256] bf16
    float*          whhS   = (float*)(smem + 100352);        // [32][260]
    float*          wsS    = (float*)(smem + 133632);        // [264] padded WS*K2
    float*          hS     = (float*)(smem + 134688);        // [256] (16B aligned)
    float*          scoreS = (float*)(smem + 135712);        // [64]
    float*          wexpS  = (float*)(smem + 135968);        // [64]
    float*          pS     = (float*)(smem + 136224);        // [512]
    float*          avS    = (float*)(smem + 138272);        // [264] padded -2*att_vec

    // att_W rows in registers: thread pair (r = tid>>1) holds 128 cols each
    float awR[128];
    { int r = tid>>1, p = tid&1;
      const float* arow = att_W + (size_t)r*256 + p*128;
      #pragma unroll
      for (int q=0;q<128;q++) awR[q] = arow[q]; }
    float Vpart = 0.f;
    { int l8 = tid & 7;
      #pragma unroll
      for (int k=0;k<32;k++) Vpart += att_vec[l8*32 + k]; }

    const float* ws_bc = ws + OFF_BC;
    for (int i=0;i<32;i++){ int lin = tid + i*512; int col = lin>>8, h = lin&255;
      bcS[col*264 + h + (h>>5)] = ws_bc[(size_t)(w*64+col)*256 + h]; }
    for (int i=0;i<32;i++){ int lin = tid + i*512; int col = lin>>8, h = lin&255;
      oeS[col*256 + h] = f2bf(outE[(size_t)(w*64+col)*256 + h]); }
    for (int i=0;i<16;i++){ int lin = tid + i*512; int r = lin>>8, j = lin&255;
      whhS[r*260 + j] = W_hh[(size_t)(w*32+r)*256 + j]; }
    if (tid < 256) avS[tid + (tid>>5)] = -2.f * att_vec[tid];
    __syncthreads();

    for (int t = 0; t < 100; ++t) {
      // ---- ctx(t-1) + LSTM (tid<256) ----
      if (tid < 256) {
        float c;
        if (t == 0) c = c0[tid];
        else {
          float raw = gload(&ws_craw[(size_t)(t-1)*256 + tid]);
          float st  = gload(&ws_stot[t-1]);
          c = raw * rcpfast(st);
        }
        const float* g = ws_graw + (size_t)t*1024;
        float ig = gload(&g[tid]),     fg = gload(&g[256+tid]);
        float gg = gload(&g[512+tid]), og = gload(&g[768+tid]);
        float cl = sigf(fg)*c + sigf(ig)*tanhfast(gg);
        float hn = sigf(og)*tanhfast(cl);
        hS[tid] = hn;
        if (w == 0) gstore(&ws_clh[(size_t)t*256 + tid], cl);
      }
      __syncthreads();
      // ---- WS = att_W @ h, fully in-WG (registers) ----
      { int r = tid>>1, p = tid&1;
        const float4* h4 = (const float4*)(hS + p*128);
        float acc = 0.f;
        #pragma unroll
        for (int i=0;i<32;i++){ float4 hv = h4[i];
          acc = fmaf(awR[4*i+0], hv.x, acc);
          acc = fmaf(awR[4*i+1], hv.y, acc);
          acc = fmaf(awR[4*i+2], hv.z, acc);
          acc = fmaf(awR[4*i+3], hv.w, acc); }
        acc += __shfl_xor(acc, 1);
        if (p == 0) wsS[r + (r>>5)] = acc * K2; }
      __syncthreads();
      // ---- scores for 64 e-columns: 8 threads/col x 32 h each ----
      { int col = tid >> 3, l8 = tid & 7;
        const float* bcR = bcS + col*264 + l8*33;
        const float* wsR = wsS + l8*33;
        const float* avR = avS + l8*33;
        float acc = Vpart;
        #pragma unroll
        for (int k=0;k<32;k++){
          float E = exp2fast(bcR[k] + wsR[k]);     // e^{2x}
          acc = fmaf(avR[k], rcpfast(E + 1.f), acc);  // v*(1-2r) summed
        }
        acc += __shfl_xor(acc,1); acc += __shfl_xor(acc,2); acc += __shfl_xor(acc,4);
        if (l8 == 0) scoreS[col] = acc; }
      __syncthreads();
      // ---- exp (no max-rescale; |score| <~ 25, fp32-safe) + denom partial ----
      if (tid < 64) {
        float ev = exp2fast(scoreS[tid] * L2E);
        wexpS[tid] = ev;
        float s = ev;
        #pragma unroll
        for (int d=1; d<64; d<<=1) s += __shfl_xor(s, d);
        if (tid == 0) gatomic_addf(&ws_stot[t], s);
      }
      __syncthreads();
      // ---- partial ctx: sum over this WG's 64 e-cols ----
      { int h = tid & 255, half = tid >> 8;
        float accp = 0.f;
        #pragma unroll
        for (int i=0;i<32;i++){ int lc = half*32 + i;
          accp = fmaf(wexpS[lc], bf2f(oeS[lc*256 + h]), accp); }
        pS[half*256 + h] = accp; }
      __syncthreads();
      if (tid < 256) gatomic_addf(&ws_craw[(size_t)t*256 + tid], pS[tid] + pS[256 + tid]);
      // ---- gates_raw(t+1) slice: rows w*32..w*32+31 ----
      if (t <= 98) {
        int r32 = tid >> 4, l16 = tid & 15;
        float acc2 = 0.f;
        #pragma unroll
        for (int q=0;q<16;q++){ int j = l16 + 16*q; acc2 = fmaf(whhS[r32*260 + j], hS[j], acc2); }
        acc2 += __shfl_xor(acc2,1); acc2 += __shfl_xor(acc2,2);
        acc2 += __shfl_xor(acc2,4); acc2 += __shfl_xor(acc2,8);
        if (l16 == 0){ int R = w*32 + r32;
          gstore(&ws_graw[(size_t)(t+1)*1024 + R], acc2 + ws_yg[(size_t)(t+1)*1024 + R]); }
      }
      fbar(flags, w, (unsigned)(t+1));
    }
    // c_final = ctx(99)
    if (w == 0 && tid < 256) {
      float raw = gload(&ws_craw[(size_t)99*256 + tid]);
      float st  = gload(&ws_stot[99]);
      out[3600 + tid] = raw * rcpfast(st);
    }
  } else if (w < 36) {
    // ---------------- MLP1: 64 rows of W1[256][512] ----------------
    float* wmS = (float*)(smem);
    float* vbS = (float*)(smem + 133632);
    int m = w - 32;
    for (int i=0;i<64;i++){ int lin = tid + i*512; int r = lin>>9, k = lin&511;
      wmS[r*520 + k + (k>>6)] = W1[(size_t)(m*64+r)*512 + k]; }
    __syncthreads();
    for (int s=0; s<100; ++s){
      fwait_sleep(flags, (unsigned)(s+1));          // step s fully accumulated
      { float val;
        if (tid < 256) val = gload(&ws_clh[(size_t)s*256 + tid]);
        else { float raw = gload(&ws_craw[(size_t)s*256 + (tid-256)]);
               float st  = gload(&ws_stot[s]);
               val = raw * rcpfast(st); }
        vbS[tid + (tid>>6)] = val; }
      __syncthreads();
      int row = tid >> 3, l8 = tid & 7;
      const float* wr = wmS + row*520 + l8*65;
      const float* vr = vbS + l8*65;
      float acc = 0.f;
      #pragma unroll
      for (int q=0;q<64;q++) acc = fmaf(wr[q], vr[q], acc);
      acc += __shfl_xor(acc,1); acc += __shfl_xor(acc,2); acc += __shfl_xor(acc,4);
      if (l8 == 0){ int i = m*64 + row; gstore(&ws_v1[(size_t)s*256 + i], fmaxf(acc + b1[i], 0.f)); }
      arrive_cnt(&fv1[s]);
    }
  } else if (w < 38) {
    // ---------------- MLP2: 128 rows of W2[256][256] ----------------
    float* wmS = (float*)(smem);
    float* vbS = (float*)(smem + 133632);
    int m = w - 36;
    for (int i=0;i<64;i++){ int lin = tid + i*512; int r = lin>>8, k = lin&255;
      wmS[r*260 + k + (k>>6)] = W2[(size_t)(m*128+r)*256 + k]; }
    __syncthreads();
    for (int s=0; s<100; ++s){
      poll_ge(&fv1[s], 4u);
      if (tid < 256) vbS[tid + (tid>>6)] = gload(&ws_v1[(size_t)s*256 + tid]);
      __syncthreads();
      int row = tid >> 2, l4 = tid & 3;
      const float* wr = wmS + row*260 + l4*65;
      const float* vr = vbS + l4*65;
      float acc = 0.f;
      #pragma unroll
      for (int q=0;q<64;q++) acc = fmaf(wr[q], vr[q], acc);
      acc += __shfl_xor(acc,1); acc += __shfl_xor(acc,2);
      if (l4 == 0){ int i = m*128 + row; gstore(&ws_v2[(size_t)s*256 + i], fmaxf(acc + b2[i], 0.f)); }
      arrive_cnt(&fv2[s]);
      __syncthreads();
    }
  } else {
    // ---------------- MLP3: W3[36][256] -> out ----------------
    float* wmS = (float*)(smem);
    float* vbS = (float*)(smem + 37440);
    for (int lin = tid; lin < 36*256; lin += 512){ int r = lin>>8, k = lin&255;
      wmS[r*260 + k + (k>>6)] = W3[(size_t)r*256 + k]; }
    __syncthreads();
    for (int s=0; s<100; ++s){
      poll_ge(&fv2[s], 2u);
      if (tid < 256) vbS[tid + (tid>>6)] = gload(&ws_v2[(size_t)s*256 + tid]);
      __syncthreads();
      if (tid < 288) {
        int row = tid >> 3, l8 = tid & 7;
        int kb = l8*32;
        const float* wr = wmS + row*260 + kb + (kb>>6);
        const float* vr = vbS + kb + (kb>>6);
        float acc = 0.f;
        #pragma unroll
        for (int q=0;q<32;q++) acc = fmaf(wr[q], vr[q], acc);
        acc += __shfl_xor(acc,1); acc += __shfl_xor(acc,2); acc += __shfl_xor(acc,4);
        if (l8 == 0) out[s*36 + row] = acc + b3[row];   // visible at kernel end
      }
      __syncthreads();
    }
  }
}

// ---------------------------------------------------------------------------
extern "C" void kernel_launch(void* const* d_in, const int* in_sizes, int n_in,
                              void* d_out, int out_size, void* d_ws, size_t ws_size,
                              hipStream_t stream) {
  (void)in_sizes; (void)n_in; (void)out_size; (void)ws_size;
  const float* Y       = (const float*)d_in[0];
  const float* h0      = (const float*)d_in[1];
  const float* c0      = (const float*)d_in[2];
  const float* outEnc  = (const float*)d_in[3];
  const float* W_ih    = (const float*)d_in[4];
  const float* W_hh    = (const float*)d_in[5];
  const float* b_ih    = (const float*)d_in[6];
  const float* b_hh    = (const float*)d_in[7];
  const float* att_W   = (const float*)d_in[8];
  const float* att_V   = (const float*)d_in[9];
  const float* att_b   = (const float*)d_in[10];
  const float* att_vec = (const float*)d_in[11];
  const float* W1      = (const float*)d_in[12];
  const float* b1      = (const float*)d_in[13];
  const float* W2      = (const float*)d_in[14];
  const float* b2      = (const float*)d_in[15];
  const float* W3      = (const float*)d_in[16];
  const float* b3      = (const float*)d_in[17];
  float* out = (float*)d_out;
  float* ws  = (float*)d_ws;

  rnn_prep<<<dim3(394), dim3(256), 0, stream>>>(Y, h0, outEnc, W_ih, W_hh, b_ih, b_hh,
                                                att_V, att_b, ws);
  rnn_main<<<dim3(39), dim3(512), 0, stream>>>(c0, outEnc, W_hh, att_W, att_vec,
                                               W1, b1, W2, b2, W3, b3, out, ws);
}